// Round 4
// baseline (511.897 us; speedup 1.0000x reference)
//
#include <hip/hip_runtime.h>
#include <stdint.h>

#define S_ROWS 100000
#define NQ     2048
#define M_POS  16
#define VOCABS 32
#define NWORD  64     // 32-query words covering all 2048 queries
#define NBLK   250    // blocks; each owns RPB support rows
#define RPB    400    // rows per block
#define KITER  25     // rows per wave (RPB / 16 waves)
#define TPB    1024

// full adder / half adder on bit-planes
__device__ __forceinline__ void FA(uint32_t a, uint32_t b, uint32_t c,
                                   uint32_t& s, uint32_t& co) {
    uint32_t x = a ^ b;
    s  = x ^ c;
    co = (a & b) | (x & c);
}
__device__ __forceinline__ void HA(uint32_t a, uint32_t b, uint32_t& s, uint32_t& co) {
    s = a ^ b; co = a & b;
}

// ---------------- fused kernel: decode + bit-sliced match-count + argmax -------
// 250 blocks x 1024 threads, 1 block/CU (128 KB LDS table).
// v2 changes vs v1 (which was barrier-lockstep-bound at 173 us):
//  - NO main-loop __syncthreads: the wave that decodes row sub IS the wave that
//    scores row sub. Broadcast of the 16 per-position values uses readlane
//    (quad butterfly leaves v_p*8 in all 4 lanes of quad p) -> wave-uniform
//    SGPR gather bases, no LDS tokbuf round-trip. 16 free-running wave
//    pipelines per CU.
//  - no-atomic table build: thread (m=sub, w) exclusively owns column
//    table[m][*][w]; LDS RMW at bank w&31 (2-way = free). Kills the 32-way
//    atomicOr bank conflicts of v1.
//  - 2-deep register prefetch of support rows (slack ~2 iterations >> 900 cyc).
__global__ __launch_bounds__(TPB, 4) void knn_fused(const int* __restrict__ utts,
                                                    const float* __restrict__ support,
                                                    uint32_t* __restrict__ best) {
    __shared__ uint32_t smem[M_POS * VOCABS * NWORD];   // 32768 words = 128 KB

    const int t    = threadIdx.x;
    const int c    = blockIdx.x;
    const int r0   = c * RPB;
    const int w    = t & 63;        // word (also lane id within wave)
    const int sub  = t >> 6;        // wave id 0..15
    const int lane = t & 63;

    // ---- build query-bitmask table, no atomics ----
    // table word index = m*2048 + v*64 + w ; bit j = (utts[m][w*32+j] == v).
    // thread (m=sub, w) owns the 32 words {m*2048 + v*64 + w}.
    {
        const int m = sub;
        uint32_t* col = smem + m * (VOCABS * NWORD) + w;
        #pragma unroll
        for (int v = 0; v < VOCABS; ++v) col[v * NWORD] = 0u;
        // this (m,w)'s 32 query tokens are contiguous: utts[m*2048 + w*32 + j]
        const int4* qp = (const int4*)(utts + m * NQ + w * 32);
        #pragma unroll
        for (int jj = 0; jj < 8; ++jj) {
            int4 q4 = qp[jj];
            col[q4.x * NWORD] |= 1u << (jj * 4 + 0);
            col[q4.y * NWORD] |= 1u << (jj * 4 + 1);
            col[q4.z * NWORD] |= 1u << (jj * 4 + 2);
            col[q4.w * NWORD] |= 1u << (jj * 4 + 3);
        }
    }
    __syncthreads();                  // table complete

    // ---- main loop: wave sub handles rows r0 + sub + 16*i, i = 0..24 ----
    uint32_t cp0=0,cp1=0,cp2=0,cp3=0,cp4=0;   // current-max count planes
    uint32_t k0p=0,k1p=0,k2p=0,k3p=0,k4p=0;   // winning-iteration planes

    const float4* gp = (const float4*)(support + (size_t)(r0 + sub) * 512) + lane * 2;
    float4 f0  = gp[0];
    float4 f1  = gp[1];
    gp += 2048;                       // +16 rows
    float4 f0n = gp[0];
    float4 f1n = gp[1];
    gp += 2048;

    const int w4 = w << 2;            // byte offset of word w

    #pragma unroll 2
    for (int i = 0; i < KITER; ++i) {
        // ---- decode current row: quad butterfly -> all lanes of quad p hold v_p*8
        float base = (float)((lane & 3) * 64);
        float v = f0.x * (base + 0.f)  + f0.y * (base + 8.f)  + f0.z * (base + 16.f) + f0.w * (base + 24.f)
                + f1.x * (base + 32.f) + f1.y * (base + 40.f) + f1.z * (base + 48.f) + f1.w * (base + 56.f);
        v += __shfl_xor(v, 1);
        v += __shfl_xor(v, 2);
        int vi = (int)(v + 0.5f);     // exact integer v_p * 8, p = lane>>2

        // ---- rotate prefetch registers; issue load for row i+2 ----
        f0 = f0n; f1 = f1n;
        if (i + 2 < KITER) {
            f0n = gp[0];
            f1n = gp[1];
            gp += 2048;
        }

        // ---- gather 16 query-mask words (wave-uniform base per position) ----
        uint32_t b[16];
        #pragma unroll
        for (int m = 0; m < M_POS; ++m) {
            int vm8 = __builtin_amdgcn_readlane(vi, 4 * m);   // SGPR: v_m * 8
            // byte addr = m*8192 + vm8*32 + w*4  -> consecutive across lanes
            b[m] = *(const uint32_t*)((const char*)smem + (m * 8192 + vm8 * 32) + w4);
        }

        // ---- CSA tree: 16 one-bit planes -> 5-bit count planes n0..n4 ----
        uint32_t s10,s11,s12,s13,s14, c10,c11,c12,c13,c14;
        FA(b[0],b[1],b[2],   s10,c10);
        FA(b[3],b[4],b[5],   s11,c11);
        FA(b[6],b[7],b[8],   s12,c12);
        FA(b[9],b[10],b[11], s13,c13);
        FA(b[12],b[13],b[14],s14,c14);
        uint32_t s2a,c2a,s2b,c2b;
        FA(s10,s11,s12, s2a,c2a);
        FA(s13,s14,b[15], s2b,c2b);
        uint32_t n0,h0;  HA(s2a,s2b, n0,h0);
        uint32_t u,cu,vv,cv,x2,cx,n1,cy;
        FA(c10,c11,c12, u,cu);
        FA(c13,c14,c2a, vv,cv);
        FA(u,vv,c2b,    x2,cx);
        HA(x2,h0,       n1,cy);
        uint32_t y4,cz,n2,cw,n3,n4;
        FA(cu,cv,cx, y4,cz);
        HA(y4,cy,    n2,cw);
        HA(cz,cw,    n3,n4);

        // ---- gt = (new count > current max), 5-bit unsigned, bit-sliced ----
        uint32_t eq = ~(n4 ^ cp4);
        uint32_t gt = n4 & ~cp4;
        gt |= eq & (n3 & ~cp3);  eq &= ~(n3 ^ cp3);
        gt |= eq & (n2 & ~cp2);  eq &= ~(n2 ^ cp2);
        gt |= eq & (n1 & ~cp1);  eq &= ~(n1 ^ cp1);
        gt |= eq & (n0 & ~cp0);

        uint32_t ng = ~gt;
        cp0 = (gt & n0) | (ng & cp0);
        cp1 = (gt & n1) | (ng & cp1);
        cp2 = (gt & n2) | (ng & cp2);
        cp3 = (gt & n3) | (ng & cp3);
        cp4 = (gt & n4) | (ng & cp4);
        // winning-iteration planes: wave-uniform masks of i's bits (SALU)
        uint32_t kb0 = 0u - (uint32_t)( i       & 1);
        uint32_t kb1 = 0u - (uint32_t)((i >> 1) & 1);
        uint32_t kb2 = 0u - (uint32_t)((i >> 2) & 1);
        uint32_t kb3 = 0u - (uint32_t)((i >> 3) & 1);
        uint32_t kb4 = 0u - (uint32_t)((i >> 4) & 1);
        k0p = (k0p & ng) | (gt & kb0);
        k1p = (k1p & ng) | (gt & kb1);
        k2p = (k2p & ng) | (gt & kb2);
        k3p = (k3p & ng) | (gt & kb3);
        k4p = (k4p & ng) | (gt & kb4);
    }

    __syncthreads();   // all table gathers done before keys overwrite smem

    // ---- extract per-query packed keys into LDS (swizzled, conflict-free) ----
    // key = (cnt << 17) | (0x1FFFF - idx); idx = r0 + kk*16 + sub
    {
        uint32_t C  = 0x1FFFFu - (uint32_t)(r0 + sub);
        int       wp = (w + sub) & 63;            // swizzle: bank = (w+sub)&31
        #pragma unroll
        for (int j = 0; j < 32; ++j) {
            uint32_t cnt = ((cp0>>j)&1u) | (((cp1>>j)&1u)<<1) | (((cp2>>j)&1u)<<2)
                         | (((cp3>>j)&1u)<<3) | (((cp4>>j)&1u)<<4);
            uint32_t kk  = ((k0p>>j)&1u) | (((k1p>>j)&1u)<<1) | (((k2p>>j)&1u)<<2)
                         | (((k3p>>j)&1u)<<3) | (((k4p>>j)&1u)<<4);
            uint32_t key = (cnt << 17) + C - (kk << 4);
            smem[j * 1024 + sub * 64 + wp] = key;
        }
    }
    __syncthreads();

    // ---- reduce over 16 subs per (word, bit), then one atomicMax per query ----
    {
        int w2 = t & 63;
        #pragma unroll
        for (int jj = 0; jj < 2; ++jj) {
            int j2 = (t >> 6) * 2 + jj;
            uint32_t bestv = 0;
            #pragma unroll
            for (int s = 0; s < 16; ++s) {
                uint32_t v = smem[j2 * 1024 + s * 64 + ((w2 + s) & 63)];
                bestv = bestv > v ? bestv : v;
            }
            atomicMax(&best[w2 * 32 + j2], bestv);
        }
    }
}

// ---------------- output kernel: one-hot from best[] ---------------------------
__global__ __launch_bounds__(256) void knn_out(const uint32_t* __restrict__ best,
                                               const int* __restrict__ meanings,
                                               float* __restrict__ out) {
    int q = blockIdx.x * 256 + threadIdx.x;
    if (q >= NQ) return;
    uint32_t b = best[q];
    int idx = 0x1FFFF - (int)(b & 0x1FFFFu);
    float* o = out + (size_t)q * 50;
    #pragma unroll
    for (int tt = 0; tt < 5; ++tt) {
        int mv = meanings[(size_t)idx * 5 + tt];
        #pragma unroll
        for (int mm = 0; mm < 10; ++mm) o[tt * 10 + mm] = (mm == mv) ? 1.0f : 0.0f;
    }
}

extern "C" void kernel_launch(void* const* d_in, const int* in_sizes, int n_in,
                              void* d_out, int out_size, void* d_ws, size_t ws_size,
                              hipStream_t stream) {
    const int*   utts     = (const int*)d_in[0];     // [16, 2048]
    const float* support  = (const float*)d_in[1];   // [100000, 512]
    const int*   meanings = (const int*)d_in[2];     // [100000, 5]
    float* out = (float*)d_out;                      // [2048, 5, 10]

    uint32_t* best = (uint32_t*)d_ws;                // 8 KB

    hipMemsetAsync(best, 0, NQ * sizeof(uint32_t), stream);
    knn_fused<<<NBLK, TPB, 0, stream>>>(utts, support, best);
    knn_out<<<NQ / 256, 256, 0, stream>>>(best, meanings, out);
}

// Round 5
// 511.882 us; speedup vs baseline: 1.0000x; 1.0000x over previous
//
#include <hip/hip_runtime.h>
#include <stdint.h>

#define S_ROWS 100000
#define NQ     2048
#define M_POS  16
#define VOCABS 32
#define NWORD  64     // 32-query words covering all 2048 queries
#define NBLK   250    // blocks; each owns RPB support rows
#define RPB    400    // rows per block
#define KITER  25     // rows per wave (RPB / 16 waves)
#define TPB    1024

// full adder / half adder on bit-planes
__device__ __forceinline__ void FA(uint32_t a, uint32_t b, uint32_t c,
                                   uint32_t& s, uint32_t& co) {
    uint32_t x = a ^ b;
    s  = x ^ c;
    co = (a & b) | (x & c);
}
__device__ __forceinline__ void HA(uint32_t a, uint32_t b, uint32_t& s, uint32_t& co) {
    s = a ^ b; co = a & b;
}

// ---------------- fused kernel: decode + bit-sliced match-count + argmax -------
// 250 blocks x 1024 threads, 1 block/CU (128 KB LDS table).
// v3 = v2 with ONE change: __launch_bounds__(1024, 1) instead of (1024, 4).
// (1024,4) made the compiler clamp to 64 VGPRs and spill ~1.3 KB/thread of the
// prefetch + b[16] live set to scratch every iteration (rocprof: 340 MB
// WRITE_SIZE, 282 MB FETCH_SIZE, 313 us). Occupancy is LDS-bound at 1 block/CU
// regardless (128 KB table), so the clamp bought nothing. With (1024,1) the
// ~70-reg live set fits with zero spill.
__global__ __launch_bounds__(TPB, 1) void knn_fused(const int* __restrict__ utts,
                                                    const float* __restrict__ support,
                                                    uint32_t* __restrict__ best) {
    __shared__ uint32_t smem[M_POS * VOCABS * NWORD];   // 32768 words = 128 KB

    const int t    = threadIdx.x;
    const int c    = blockIdx.x;
    const int r0   = c * RPB;
    const int w    = t & 63;        // word (also lane id within wave)
    const int sub  = t >> 6;        // wave id 0..15
    const int lane = t & 63;

    // ---- build query-bitmask table, no atomics ----
    // table word index = m*2048 + v*64 + w ; bit j = (utts[m][w*32+j] == v).
    // thread (m=sub, w) owns the 32 words {m*2048 + v*64 + w}.
    {
        const int m = sub;
        uint32_t* col = smem + m * (VOCABS * NWORD) + w;
        #pragma unroll
        for (int v = 0; v < VOCABS; ++v) col[v * NWORD] = 0u;
        // this (m,w)'s 32 query tokens are contiguous: utts[m*2048 + w*32 + j]
        const int4* qp = (const int4*)(utts + m * NQ + w * 32);
        #pragma unroll
        for (int jj = 0; jj < 8; ++jj) {
            int4 q4 = qp[jj];
            col[q4.x * NWORD] |= 1u << (jj * 4 + 0);
            col[q4.y * NWORD] |= 1u << (jj * 4 + 1);
            col[q4.z * NWORD] |= 1u << (jj * 4 + 2);
            col[q4.w * NWORD] |= 1u << (jj * 4 + 3);
        }
    }
    __syncthreads();                  // table complete

    // ---- main loop: wave sub handles rows r0 + sub + 16*i, i = 0..24 ----
    uint32_t cp0=0,cp1=0,cp2=0,cp3=0,cp4=0;   // current-max count planes
    uint32_t k0p=0,k1p=0,k2p=0,k3p=0,k4p=0;   // winning-iteration planes

    const float4* gp = (const float4*)(support + (size_t)(r0 + sub) * 512) + lane * 2;
    float4 f0  = gp[0];
    float4 f1  = gp[1];
    gp += 2048;                       // +16 rows
    float4 f0n = gp[0];
    float4 f1n = gp[1];
    gp += 2048;

    const int w4 = w << 2;            // byte offset of word w

    #pragma unroll 2
    for (int i = 0; i < KITER; ++i) {
        // ---- decode current row: quad butterfly -> all lanes of quad p hold v_p*8
        float base = (float)((lane & 3) * 64);
        float v = f0.x * (base + 0.f)  + f0.y * (base + 8.f)  + f0.z * (base + 16.f) + f0.w * (base + 24.f)
                + f1.x * (base + 32.f) + f1.y * (base + 40.f) + f1.z * (base + 48.f) + f1.w * (base + 56.f);
        v += __shfl_xor(v, 1);
        v += __shfl_xor(v, 2);
        int vi = (int)(v + 0.5f);     // exact integer v_p * 8, p = lane>>2

        // ---- rotate prefetch registers; issue load for row i+2 ----
        f0 = f0n; f1 = f1n;
        if (i + 2 < KITER) {
            f0n = gp[0];
            f1n = gp[1];
            gp += 2048;
        }

        // ---- gather 16 query-mask words (wave-uniform base per position) ----
        uint32_t b[16];
        #pragma unroll
        for (int m = 0; m < M_POS; ++m) {
            int vm8 = __builtin_amdgcn_readlane(vi, 4 * m);   // SGPR: v_m * 8
            // byte addr = m*8192 + vm8*32 + w*4  -> consecutive across lanes
            b[m] = *(const uint32_t*)((const char*)smem + (m * 8192 + vm8 * 32) + w4);
        }

        // ---- CSA tree: 16 one-bit planes -> 5-bit count planes n0..n4 ----
        uint32_t s10,s11,s12,s13,s14, c10,c11,c12,c13,c14;
        FA(b[0],b[1],b[2],   s10,c10);
        FA(b[3],b[4],b[5],   s11,c11);
        FA(b[6],b[7],b[8],   s12,c12);
        FA(b[9],b[10],b[11], s13,c13);
        FA(b[12],b[13],b[14],s14,c14);
        uint32_t s2a,c2a,s2b,c2b;
        FA(s10,s11,s12, s2a,c2a);
        FA(s13,s14,b[15], s2b,c2b);
        uint32_t n0,h0;  HA(s2a,s2b, n0,h0);
        uint32_t u,cu,vv,cv,x2,cx,n1,cy;
        FA(c10,c11,c12, u,cu);
        FA(c13,c14,c2a, vv,cv);
        FA(u,vv,c2b,    x2,cx);
        HA(x2,h0,       n1,cy);
        uint32_t y4,cz,n2,cw,n3,n4;
        FA(cu,cv,cx, y4,cz);
        HA(y4,cy,    n2,cw);
        HA(cz,cw,    n3,n4);

        // ---- gt = (new count > current max), 5-bit unsigned, bit-sliced ----
        uint32_t eq = ~(n4 ^ cp4);
        uint32_t gt = n4 & ~cp4;
        gt |= eq & (n3 & ~cp3);  eq &= ~(n3 ^ cp3);
        gt |= eq & (n2 & ~cp2);  eq &= ~(n2 ^ cp2);
        gt |= eq & (n1 & ~cp1);  eq &= ~(n1 ^ cp1);
        gt |= eq & (n0 & ~cp0);

        uint32_t ng = ~gt;
        cp0 = (gt & n0) | (ng & cp0);
        cp1 = (gt & n1) | (ng & cp1);
        cp2 = (gt & n2) | (ng & cp2);
        cp3 = (gt & n3) | (ng & cp3);
        cp4 = (gt & n4) | (ng & cp4);
        // winning-iteration planes: wave-uniform masks of i's bits (SALU)
        uint32_t kb0 = 0u - (uint32_t)( i       & 1);
        uint32_t kb1 = 0u - (uint32_t)((i >> 1) & 1);
        uint32_t kb2 = 0u - (uint32_t)((i >> 2) & 1);
        uint32_t kb3 = 0u - (uint32_t)((i >> 3) & 1);
        uint32_t kb4 = 0u - (uint32_t)((i >> 4) & 1);
        k0p = (k0p & ng) | (gt & kb0);
        k1p = (k1p & ng) | (gt & kb1);
        k2p = (k2p & ng) | (gt & kb2);
        k3p = (k3p & ng) | (gt & kb3);
        k4p = (k4p & ng) | (gt & kb4);
    }

    __syncthreads();   // all table gathers done before keys overwrite smem

    // ---- extract per-query packed keys into LDS (swizzled, conflict-free) ----
    // key = (cnt << 17) | (0x1FFFF - idx); idx = r0 + kk*16 + sub
    {
        uint32_t C  = 0x1FFFFu - (uint32_t)(r0 + sub);
        int       wp = (w + sub) & 63;            // swizzle: bank = (w+sub)&31
        #pragma unroll
        for (int j = 0; j < 32; ++j) {
            uint32_t cnt = ((cp0>>j)&1u) | (((cp1>>j)&1u)<<1) | (((cp2>>j)&1u)<<2)
                         | (((cp3>>j)&1u)<<3) | (((cp4>>j)&1u)<<4);
            uint32_t kk  = ((k0p>>j)&1u) | (((k1p>>j)&1u)<<1) | (((k2p>>j)&1u)<<2)
                         | (((k3p>>j)&1u)<<3) | (((k4p>>j)&1u)<<4);
            uint32_t key = (cnt << 17) + C - (kk << 4);
            smem[j * 1024 + sub * 64 + wp] = key;
        }
    }
    __syncthreads();

    // ---- reduce over 16 subs per (word, bit), then one atomicMax per query ----
    {
        int w2 = t & 63;
        #pragma unroll
        for (int jj = 0; jj < 2; ++jj) {
            int j2 = (t >> 6) * 2 + jj;
            uint32_t bestv = 0;
            #pragma unroll
            for (int s = 0; s < 16; ++s) {
                uint32_t v = smem[j2 * 1024 + s * 64 + ((w2 + s) & 63)];
                bestv = bestv > v ? bestv : v;
            }
            atomicMax(&best[w2 * 32 + j2], bestv);
        }
    }
}

// ---------------- output kernel: one-hot from best[] ---------------------------
__global__ __launch_bounds__(256) void knn_out(const uint32_t* __restrict__ best,
                                               const int* __restrict__ meanings,
                                               float* __restrict__ out) {
    int q = blockIdx.x * 256 + threadIdx.x;
    if (q >= NQ) return;
    uint32_t b = best[q];
    int idx = 0x1FFFF - (int)(b & 0x1FFFFu);
    float* o = out + (size_t)q * 50;
    #pragma unroll
    for (int tt = 0; tt < 5; ++tt) {
        int mv = meanings[(size_t)idx * 5 + tt];
        #pragma unroll
        for (int mm = 0; mm < 10; ++mm) o[tt * 10 + mm] = (mm == mv) ? 1.0f : 0.0f;
    }
}

extern "C" void kernel_launch(void* const* d_in, const int* in_sizes, int n_in,
                              void* d_out, int out_size, void* d_ws, size_t ws_size,
                              hipStream_t stream) {
    const int*   utts     = (const int*)d_in[0];     // [16, 2048]
    const float* support  = (const float*)d_in[1];   // [100000, 512]
    const int*   meanings = (const int*)d_in[2];     // [100000, 5]
    float* out = (float*)d_out;                      // [2048, 5, 10]

    uint32_t* best = (uint32_t*)d_ws;                // 8 KB

    hipMemsetAsync(best, 0, NQ * sizeof(uint32_t), stream);
    knn_fused<<<NBLK, TPB, 0, stream>>>(utts, support, best);
    knn_out<<<NQ / 256, 256, 0, stream>>>(best, meanings, out);
}

// Round 6
// 368.535 us; speedup vs baseline: 1.3890x; 1.3890x over previous
//
#include <hip/hip_runtime.h>
#include <stdint.h>

#define S_ROWS 100000
#define NQ     2048
#define M_POS  16
#define VOCABS 32
#define NWORD  64     // 32-query words covering all 2048 queries
#define NBLK   250    // blocks; each owns RPB support rows
#define RPB    400    // rows per block
#define KITER  25     // rows per wave (RPB / 16 waves)
#define TPB    1024

// full adder / half adder on bit-planes
__device__ __forceinline__ void FA(uint32_t a, uint32_t b, uint32_t c,
                                   uint32_t& s, uint32_t& co) {
    uint32_t x = a ^ b;
    s  = x ^ c;
    co = (a & b) | (x & c);
}
__device__ __forceinline__ void HA(uint32_t a, uint32_t b, uint32_t& s, uint32_t& co) {
    s = a ^ b; co = a & b;
}

// ---------------- fused kernel: decode + bit-sliced match-count + argmax -------
// 250 blocks x 1024 threads, 1 block/CU (128 KB LDS table).
// v4 = v3 with the REAL spill fix. v2/v3 both allocated 64 VGPRs and spilled
// ~1.4 KB/thread (340 MB WRITE_SIZE): LLVM's scheduler targets 8 waves/EU
// (64 VGPRs) for memory-heavy kernels and spills to get there, even though
// occupancy is LDS-pinned at 1 block/CU = 4 waves/EU. launch_bounds' 2nd arg
// is only a FLOOR on waves/EU, it cannot raise the allocator's target.
// amdgpu_waves_per_eu(4,4) pins the target to the true occupancy -> 128-VGPR
// budget -> no spill. unroll 1 keeps the live set compact as insurance.
__global__ __launch_bounds__(TPB)
__attribute__((amdgpu_waves_per_eu(4, 4)))
void knn_fused(const int* __restrict__ utts,
               const float* __restrict__ support,
               uint32_t* __restrict__ best) {
    __shared__ uint32_t smem[M_POS * VOCABS * NWORD];   // 32768 words = 128 KB

    const int t    = threadIdx.x;
    const int c    = blockIdx.x;
    const int r0   = c * RPB;
    const int w    = t & 63;        // word (also lane id within wave)
    const int sub  = t >> 6;        // wave id 0..15
    const int lane = t & 63;

    // ---- build query-bitmask table, no atomics ----
    // table word index = m*2048 + v*64 + w ; bit j = (utts[m][w*32+j] == v).
    // thread (m=sub, w) owns the 32 words {m*2048 + v*64 + w}.
    {
        const int m = sub;
        uint32_t* col = smem + m * (VOCABS * NWORD) + w;
        #pragma unroll
        for (int v = 0; v < VOCABS; ++v) col[v * NWORD] = 0u;
        // this (m,w)'s 32 query tokens are contiguous: utts[m*2048 + w*32 + j]
        const int4* qp = (const int4*)(utts + m * NQ + w * 32);
        #pragma unroll
        for (int jj = 0; jj < 8; ++jj) {
            int4 q4 = qp[jj];
            col[q4.x * NWORD] |= 1u << (jj * 4 + 0);
            col[q4.y * NWORD] |= 1u << (jj * 4 + 1);
            col[q4.z * NWORD] |= 1u << (jj * 4 + 2);
            col[q4.w * NWORD] |= 1u << (jj * 4 + 3);
        }
    }
    __syncthreads();                  // table complete

    // ---- main loop: wave sub handles rows r0 + sub + 16*i, i = 0..24 ----
    uint32_t cp0=0,cp1=0,cp2=0,cp3=0,cp4=0;   // current-max count planes
    uint32_t k0p=0,k1p=0,k2p=0,k3p=0,k4p=0;   // winning-iteration planes

    const float4* gp = (const float4*)(support + (size_t)(r0 + sub) * 512) + lane * 2;
    float4 f0  = gp[0];
    float4 f1  = gp[1];
    gp += 2048;                       // +16 rows
    float4 f0n = gp[0];
    float4 f1n = gp[1];
    gp += 2048;

    const int w4 = w << 2;            // byte offset of word w

    #pragma unroll 1
    for (int i = 0; i < KITER; ++i) {
        // ---- decode current row: quad butterfly -> all lanes of quad p hold v_p*8
        float base = (float)((lane & 3) * 64);
        float v = f0.x * (base + 0.f)  + f0.y * (base + 8.f)  + f0.z * (base + 16.f) + f0.w * (base + 24.f)
                + f1.x * (base + 32.f) + f1.y * (base + 40.f) + f1.z * (base + 48.f) + f1.w * (base + 56.f);
        v += __shfl_xor(v, 1);
        v += __shfl_xor(v, 2);
        int vi = (int)(v + 0.5f);     // exact integer v_p * 8, p = lane>>2

        // ---- rotate prefetch registers; issue load for row i+2 ----
        f0 = f0n; f1 = f1n;
        if (i + 2 < KITER) {
            f0n = gp[0];
            f1n = gp[1];
            gp += 2048;
        }

        // ---- gather 16 query-mask words (wave-uniform base per position) ----
        uint32_t b[16];
        #pragma unroll
        for (int m = 0; m < M_POS; ++m) {
            int vm8 = __builtin_amdgcn_readlane(vi, 4 * m);   // SGPR: v_m * 8
            // byte addr = m*8192 + vm8*32 + w*4  -> consecutive across lanes
            b[m] = *(const uint32_t*)((const char*)smem + (m * 8192 + vm8 * 32) + w4);
        }

        // ---- CSA tree: 16 one-bit planes -> 5-bit count planes n0..n4 ----
        uint32_t s10,s11,s12,s13,s14, c10,c11,c12,c13,c14;
        FA(b[0],b[1],b[2],   s10,c10);
        FA(b[3],b[4],b[5],   s11,c11);
        FA(b[6],b[7],b[8],   s12,c12);
        FA(b[9],b[10],b[11], s13,c13);
        FA(b[12],b[13],b[14],s14,c14);
        uint32_t s2a,c2a,s2b,c2b;
        FA(s10,s11,s12, s2a,c2a);
        FA(s13,s14,b[15], s2b,c2b);
        uint32_t n0,h0;  HA(s2a,s2b, n0,h0);
        uint32_t u,cu,vv,cv,x2,cx,n1,cy;
        FA(c10,c11,c12, u,cu);
        FA(c13,c14,c2a, vv,cv);
        FA(u,vv,c2b,    x2,cx);
        HA(x2,h0,       n1,cy);
        uint32_t y4,cz,n2,cw,n3,n4;
        FA(cu,cv,cx, y4,cz);
        HA(y4,cy,    n2,cw);
        HA(cz,cw,    n3,n4);

        // ---- gt = (new count > current max), 5-bit unsigned, bit-sliced ----
        uint32_t eq = ~(n4 ^ cp4);
        uint32_t gt = n4 & ~cp4;
        gt |= eq & (n3 & ~cp3);  eq &= ~(n3 ^ cp3);
        gt |= eq & (n2 & ~cp2);  eq &= ~(n2 ^ cp2);
        gt |= eq & (n1 & ~cp1);  eq &= ~(n1 ^ cp1);
        gt |= eq & (n0 & ~cp0);

        uint32_t ng = ~gt;
        cp0 = (gt & n0) | (ng & cp0);
        cp1 = (gt & n1) | (ng & cp1);
        cp2 = (gt & n2) | (ng & cp2);
        cp3 = (gt & n3) | (ng & cp3);
        cp4 = (gt & n4) | (ng & cp4);
        // winning-iteration planes: wave-uniform masks of i's bits (SALU)
        uint32_t kb0 = 0u - (uint32_t)( i       & 1);
        uint32_t kb1 = 0u - (uint32_t)((i >> 1) & 1);
        uint32_t kb2 = 0u - (uint32_t)((i >> 2) & 1);
        uint32_t kb3 = 0u - (uint32_t)((i >> 3) & 1);
        uint32_t kb4 = 0u - (uint32_t)((i >> 4) & 1);
        k0p = (k0p & ng) | (gt & kb0);
        k1p = (k1p & ng) | (gt & kb1);
        k2p = (k2p & ng) | (gt & kb2);
        k3p = (k3p & ng) | (gt & kb3);
        k4p = (k4p & ng) | (gt & kb4);
    }

    __syncthreads();   // all table gathers done before keys overwrite smem

    // ---- extract per-query packed keys into LDS (swizzled, conflict-free) ----
    // key = (cnt << 17) | (0x1FFFF - idx); idx = r0 + kk*16 + sub
    {
        uint32_t C  = 0x1FFFFu - (uint32_t)(r0 + sub);
        int       wp = (w + sub) & 63;            // swizzle: bank = (w+sub)&31
        #pragma unroll
        for (int j = 0; j < 32; ++j) {
            uint32_t cnt = ((cp0>>j)&1u) | (((cp1>>j)&1u)<<1) | (((cp2>>j)&1u)<<2)
                         | (((cp3>>j)&1u)<<3) | (((cp4>>j)&1u)<<4);
            uint32_t kk  = ((k0p>>j)&1u) | (((k1p>>j)&1u)<<1) | (((k2p>>j)&1u)<<2)
                         | (((k3p>>j)&1u)<<3) | (((k4p>>j)&1u)<<4);
            uint32_t key = (cnt << 17) + C - (kk << 4);
            smem[j * 1024 + sub * 64 + wp] = key;
        }
    }
    __syncthreads();

    // ---- reduce over 16 subs per (word, bit), then one atomicMax per query ----
    {
        int w2 = t & 63;
        #pragma unroll
        for (int jj = 0; jj < 2; ++jj) {
            int j2 = (t >> 6) * 2 + jj;
            uint32_t bestv = 0;
            #pragma unroll
            for (int s = 0; s < 16; ++s) {
                uint32_t v = smem[j2 * 1024 + s * 64 + ((w2 + s) & 63)];
                bestv = bestv > v ? bestv : v;
            }
            atomicMax(&best[w2 * 32 + j2], bestv);
        }
    }
}

// ---------------- output kernel: one-hot from best[] ---------------------------
__global__ __launch_bounds__(256) void knn_out(const uint32_t* __restrict__ best,
                                               const int* __restrict__ meanings,
                                               float* __restrict__ out) {
    int q = blockIdx.x * 256 + threadIdx.x;
    if (q >= NQ) return;
    uint32_t b = best[q];
    int idx = 0x1FFFF - (int)(b & 0x1FFFFu);
    float* o = out + (size_t)q * 50;
    #pragma unroll
    for (int tt = 0; tt < 5; ++tt) {
        int mv = meanings[(size_t)idx * 5 + tt];
        #pragma unroll
        for (int mm = 0; mm < 10; ++mm) o[tt * 10 + mm] = (mm == mv) ? 1.0f : 0.0f;
    }
}

extern "C" void kernel_launch(void* const* d_in, const int* in_sizes, int n_in,
                              void* d_out, int out_size, void* d_ws, size_t ws_size,
                              hipStream_t stream) {
    const int*   utts     = (const int*)d_in[0];     // [16, 2048]
    const float* support  = (const float*)d_in[1];   // [100000, 512]
    const int*   meanings = (const int*)d_in[2];     // [100000, 5]
    float* out = (float*)d_out;                      // [2048, 5, 10]

    uint32_t* best = (uint32_t*)d_ws;                // 8 KB

    hipMemsetAsync(best, 0, NQ * sizeof(uint32_t), stream);
    knn_fused<<<NBLK, TPB, 0, stream>>>(utts, support, best);
    knn_out<<<NQ / 256, 256, 0, stream>>>(best, meanings, out);
}

// Round 8
// 314.333 us; speedup vs baseline: 1.6285x; 1.1724x over previous
//
#include <hip/hip_runtime.h>
#include <stdint.h>

#define S_ROWS 100000
#define NQ     2048
#define M_POS  16
#define VOCABS 32
#define WPB    8      // 32-query words per score block (256 queries)
#define GROUPS 8      // 2048 / 256
#define CHUNKS 125
#define RC     800    // rows per chunk
#define KITER  25     // RC / 32
#define KPAD   264    // padded stride for keys transpose (conflict-free)

// ---------------- kernel 1: decode one-hot support rows to token bytes (v*8) ----
// Also zero-inits best[] (workspace is re-poisoned each iteration).
__global__ __launch_bounds__(256) void knn_decode(const float* __restrict__ support,
                                                  uint8_t* __restrict__ tok,
                                                  uint32_t* __restrict__ best) {
    if (blockIdx.x < 8) best[blockIdx.x * 256 + threadIdx.x] = 0u;
    int wave = (blockIdx.x * 256 + threadIdx.x) >> 6;   // one wave per row
    int lane = threadIdx.x & 63;
    if (wave >= S_ROWS) return;
    const float4* rowp = (const float4*)(support + (size_t)wave * 512) + lane * 2;
    float4 f0 = rowp[0];
    float4 f1 = rowp[1];
    float base = (float)((lane & 3) * 64);
    float v = f0.x * (base + 0.f)  + f0.y * (base + 8.f)  + f0.z * (base + 16.f) + f0.w * (base + 24.f)
            + f1.x * (base + 32.f) + f1.y * (base + 40.f) + f1.z * (base + 48.f) + f1.w * (base + 56.f);
    v += __shfl_xor(v, 1);
    v += __shfl_xor(v, 2);
    if ((lane & 3) == 0) {
        int p = lane >> 2;
        tok[(size_t)wave * 16 + p] = (uint8_t)(v + 0.5f);   // v*8, <=248
    }
}

// full adder / half adder on bit-planes
__device__ __forceinline__ void FA(uint32_t a, uint32_t b, uint32_t c,
                                   uint32_t& s, uint32_t& co) {
    uint32_t x = a ^ b;
    s  = x ^ c;
    co = (a & b) | (x & c);
}
__device__ __forceinline__ void HA(uint32_t a, uint32_t b, uint32_t& s, uint32_t& co) {
    s = a ^ b; co = a & b;
}

__device__ __forceinline__ void gather16(const uint32_t* __restrict__ tw, uint4 ta,
                                         uint32_t b[16]) {
    b[0]  = tw[ (ta.x        & 0xFFu) +  0*256];
    b[1]  = tw[((ta.x >> 8)  & 0xFFu) +  1*256];
    b[2]  = tw[((ta.x >> 16) & 0xFFu) +  2*256];
    b[3]  = tw[((ta.x >> 24)        ) +  3*256];
    b[4]  = tw[ (ta.y        & 0xFFu) +  4*256];
    b[5]  = tw[((ta.y >> 8)  & 0xFFu) +  5*256];
    b[6]  = tw[((ta.y >> 16) & 0xFFu) +  6*256];
    b[7]  = tw[((ta.y >> 24)        ) +  7*256];
    b[8]  = tw[ (ta.z        & 0xFFu) +  8*256];
    b[9]  = tw[((ta.z >> 8)  & 0xFFu) +  9*256];
    b[10] = tw[((ta.z >> 16) & 0xFFu) + 10*256];
    b[11] = tw[((ta.z >> 24)        ) + 11*256];
    b[12] = tw[ (ta.w        & 0xFFu) + 12*256];
    b[13] = tw[((ta.w >> 8)  & 0xFFu) + 13*256];
    b[14] = tw[((ta.w >> 16) & 0xFFu) + 14*256];
    b[15] = tw[((ta.w >> 24)        ) + 15*256];
}

// CSA popcount of 16 bit-planes + bit-sliced max/argmax update. k via SALU masks.
__device__ __forceinline__ void score_row(const uint32_t b[16], int k,
        uint32_t& cp0, uint32_t& cp1, uint32_t& cp2, uint32_t& cp3, uint32_t& cp4,
        uint32_t& k0p, uint32_t& k1p, uint32_t& k2p, uint32_t& k3p, uint32_t& k4p) {
    uint32_t s10,s11,s12,s13,s14, c10,c11,c12,c13,c14;
    FA(b[0],b[1],b[2],   s10,c10);
    FA(b[3],b[4],b[5],   s11,c11);
    FA(b[6],b[7],b[8],   s12,c12);
    FA(b[9],b[10],b[11], s13,c13);
    FA(b[12],b[13],b[14],s14,c14);
    uint32_t s2a,c2a,s2b,c2b;
    FA(s10,s11,s12, s2a,c2a);
    FA(s13,s14,b[15], s2b,c2b);
    uint32_t n0,h0;  HA(s2a,s2b, n0,h0);
    uint32_t u,cu,vv,cv,x2,cx,n1,cy;
    FA(c10,c11,c12, u,cu);
    FA(c13,c14,c2a, vv,cv);
    FA(u,vv,c2b,    x2,cx);
    HA(x2,h0,       n1,cy);
    uint32_t y4,cz,n2,cw,n3,n4;
    FA(cu,cv,cx, y4,cz);
    HA(y4,cy,    n2,cw);
    HA(cz,cw,    n3,n4);

    uint32_t eq = ~(n4 ^ cp4);
    uint32_t gt = n4 & ~cp4;
    gt |= eq & (n3 & ~cp3);  eq &= ~(n3 ^ cp3);
    gt |= eq & (n2 & ~cp2);  eq &= ~(n2 ^ cp2);
    gt |= eq & (n1 & ~cp1);  eq &= ~(n1 ^ cp1);
    gt |= eq & (n0 & ~cp0);

    uint32_t ng = ~gt;
    cp0 = (gt & n0) | (ng & cp0);
    cp1 = (gt & n1) | (ng & cp1);
    cp2 = (gt & n2) | (ng & cp2);
    cp3 = (gt & n3) | (ng & cp3);
    cp4 = (gt & n4) | (ng & cp4);
    uint32_t kb0 = 0u - (uint32_t)( k       & 1);
    uint32_t kb1 = 0u - (uint32_t)((k >> 1) & 1);
    uint32_t kb2 = 0u - (uint32_t)((k >> 2) & 1);
    uint32_t kb3 = 0u - (uint32_t)((k >> 3) & 1);
    uint32_t kb4 = 0u - (uint32_t)((k >> 4) & 1);
    k0p = (k0p & ng) | (gt & kb0);
    k1p = (k1p & ng) | (gt & kb1);
    k2p = (k2p & ng) | (gt & kb2);
    k3p = (k3p & ng) | (gt & kb3);
    k4p = (k4p & ng) | (gt & kb4);
}

// ---------------- kernel 2: bit-sliced match-count + argmax --------------------
// Round-1 structure (256 thr, 16 KB table, grid 1000) + 2-row ILP: issue all 32
// LDS gathers for rows (2j, 2j+1) before consuming either -> 2x memory-level
// parallelism against ds_read latency. ta loads prefetched 1 pair deep.
// waves_per_eu(4,4) pins the allocator to the true grid-bound occupancy
// (~16 waves/CU = 4/EU, 128-VGPR budget) so it doesn't chase 8/EU and spill
// (the round-4/5 fused-kernel failure mode).
__global__ __launch_bounds__(256, 4)
__attribute__((amdgpu_waves_per_eu(4, 4)))
void knn_score(const int* __restrict__ utts,
               const uint8_t* __restrict__ tok,
               uint32_t* __restrict__ best) {
    __shared__ uint32_t smem[32 * KPAD];               // 33.8 KB
    uint32_t* table = smem;                            // first 4096 words during main loop
    uint32_t* keys  = smem;                            // whole buffer, after main loop

    const int bid = blockIdx.x;
    const int g   = bid & 7;          // query group (256 queries)
    const int c   = bid >> 3;         // row chunk
    const int t   = threadIdx.x;

    // zero table
    #pragma unroll
    for (int i = 0; i < 16; ++i) table[t + 256 * i] = 0u;
    __syncthreads();

    // build query-bitmask table: B[m][v][w] bit j = (utts[m][g*256+w*32+j] == v)
    {
        int q = g * 256 + t;
        int wb = t >> 5, j = t & 31;
        #pragma unroll
        for (int m = 0; m < M_POS; ++m) {
            int v = utts[m * NQ + q];
            atomicOr(&table[(m * VOCABS + v) * WPB + wb], 1u << j);
        }
    }
    __syncthreads();

    const int w   = t & 7;            // which 32-query word this thread scores
    const int sub = t >> 3;           // row sub-lane (0..31)
    const int r0  = c * RC;
    const uint32_t* tw = table + w;

    uint32_t cp0=0,cp1=0,cp2=0,cp3=0,cp4=0;   // current-max count planes
    uint32_t k0p=0,k1p=0,k2p=0,k3p=0,k4p=0;   // winning-iteration planes

    const uint4* tbase = (const uint4*)(tok + (size_t)(r0 + sub) * 16);

    // pair loop: k = 2j, 2j+1 for j = 0..11, epilogue k = 24
    uint4 tA = tbase[0];
    uint4 tB = tbase[32];
    #pragma unroll 1
    for (int j = 0; j < 12; ++j) {
        uint4 tAn, tBn;
        if (j < 11) {
            tAn = tbase[32 * (2 * j + 2)];
            tBn = tbase[32 * (2 * j + 3)];
        } else {
            tAn = tbase[32 * 24];          // epilogue row
            tBn = tAn;
        }
        uint32_t b0[16], b1[16];
        gather16(tw, tA, b0);              // 32 independent ds_reads issued
        gather16(tw, tB, b1);              // before either CSA consumes
        score_row(b0, 2 * j,     cp0,cp1,cp2,cp3,cp4, k0p,k1p,k2p,k3p,k4p);
        score_row(b1, 2 * j + 1, cp0,cp1,cp2,cp3,cp4, k0p,k1p,k2p,k3p,k4p);
        tA = tAn; tB = tBn;
    }
    {   // epilogue: k = 24
        uint32_t b0[16];
        gather16(tw, tA, b0);
        score_row(b0, 24, cp0,cp1,cp2,cp3,cp4, k0p,k1p,k2p,k3p,k4p);
    }

    __syncthreads();   // all table gathers done before keys overwrite the union

    // extract per-query packed keys into LDS (conflict-free layout, no atomics)
    // key = (cnt << 17) | (0x1FFFF - idx); idx = r0 + sub + 32*kk
    {
        uint32_t C = 0x1FFFFu - (uint32_t)(r0 + sub);
        #pragma unroll
        for (int j = 0; j < 32; ++j) {
            uint32_t cnt = ((cp0>>j)&1u) | (((cp1>>j)&1u)<<1) | (((cp2>>j)&1u)<<2)
                         | (((cp3>>j)&1u)<<3) | (((cp4>>j)&1u)<<4);
            uint32_t kk  = ((k0p>>j)&1u) | (((k1p>>j)&1u)<<1) | (((k2p>>j)&1u)<<2)
                         | (((k3p>>j)&1u)<<3) | (((k4p>>j)&1u)<<4);
            uint32_t key = (cnt << 17) + C - (kk << 5);
            keys[j * KPAD + t] = key;           // bank = t&31: conflict-free
        }
    }
    __syncthreads();

    // reduce: thread t owns query (w2 = t&7, j2 = t>>3); max over 32 sub-threads,
    // then one device-scope atomicMax per (query, block) -> 125 ops/address.
    {
        int w2 = t & 7, j2 = t >> 3;
        const uint32_t* kp = keys + j2 * KPAD + w2;
        uint32_t bestv = 0;
        #pragma unroll
        for (int i = 0; i < 32; ++i) {
            uint32_t v = kp[8 * i];             // bank = (8*(j2+i)+w2)&31: 2-way max
            bestv = bestv > v ? bestv : v;
        }
        atomicMax(&best[g * 256 + w2 * 32 + j2], bestv);
    }
}

// ---------------- kernel 3: one-hot output from fused best[] -------------------
__global__ __launch_bounds__(256) void knn_out(const uint32_t* __restrict__ best,
                                               const int* __restrict__ meanings,
                                               float* __restrict__ out) {
    int q = blockIdx.x * 256 + threadIdx.x;
    if (q >= NQ) return;
    uint32_t b = best[q];
    int idx = 0x1FFFF - (int)(b & 0x1FFFFu);
    float* o = out + (size_t)q * 50;
    #pragma unroll
    for (int tt = 0; tt < 5; ++tt) {
        int mv = meanings[(size_t)idx * 5 + tt];
        #pragma unroll
        for (int mm = 0; mm < 10; ++mm) o[tt * 10 + mm] = (mm == mv) ? 1.0f : 0.0f;
    }
}

extern "C" void kernel_launch(void* const* d_in, const int* in_sizes, int n_in,
                              void* d_out, int out_size, void* d_ws, size_t ws_size,
                              hipStream_t stream) {
    const int*   utts     = (const int*)d_in[0];     // [16, 2048]
    const float* support  = (const float*)d_in[1];   // [100000, 512]
    const int*   meanings = (const int*)d_in[2];     // [100000, 5]
    float* out = (float*)d_out;                      // [2048, 5, 10]

    uint8_t*  tok  = (uint8_t*)d_ws;                                   // 1.6 MB
    uint32_t* best = (uint32_t*)((char*)d_ws + (size_t)S_ROWS * 16);   // 8 KB

    knn_decode<<<(S_ROWS + 3) / 4, 256, 0, stream>>>(support, tok, best);
    knn_score<<<GROUPS * CHUNKS, 256, 0, stream>>>(utts, tok, best);
    knn_out<<<NQ / 256, 256, 0, stream>>>(best, meanings, out);
}